// Round 10
// baseline (112.545 us; speedup 1.0000x reference)
//
#include <hip/hip_runtime.h>

// ---------------------------------------------------------------------------
// DotProductAttention: out[b,i,f] = softmax_j(<K_i, Q_j>) @ V[j,f]
// Q single bf16 plane; K hi+lo (registers); 32x32x16 bf16 MFMA.
// K pre-scaled by log2(e) -> exp2-domain softmax. B=8, L=4096, F=64.
// R10: barrier-free LDS-free attn (fragments streamed from L2), 2-wave blocks,
//      XCD-aligned batch mapping; W hi/lo pre-split in prep kernel.
// ---------------------------------------------------------------------------

typedef unsigned short u16;
typedef __attribute__((ext_vector_type(4))) unsigned int u32x4;
typedef __attribute__((ext_vector_type(4))) float f32x4;
typedef __attribute__((ext_vector_type(16))) float f32x16;
typedef __attribute__((ext_vector_type(2))) float f32x2;
typedef __attribute__((ext_vector_type(8))) short s16x8;

#define MFMA32(a, bb, c) __builtin_amdgcn_mfma_f32_32x32x16_bf16((a), (bb), (c), 0, 0, 0)
#define MFMA16(a, bb, c) __builtin_amdgcn_mfma_f32_16x16x32_bf16((a), (bb), (c), 0, 0, 0)

#if __has_builtin(__builtin_amdgcn_exp2f)
#define FEXP2(x) __builtin_amdgcn_exp2f(x)
#else
#define FEXP2(x) exp2f(x)
#endif

__device__ __forceinline__ short f2bf(float x) {
    unsigned u = __builtin_bit_cast(unsigned, x);
    u += 0x7fffu + ((u >> 16) & 1u);   // round-to-nearest-even
    return (short)(u >> 16);
}
__device__ __forceinline__ float bf2f(short h) {
    unsigned u = ((unsigned)(u16)h) << 16;
    return __builtin_bit_cast(float, u);
}
__device__ __forceinline__ f32x4 zero4() { f32x4 r = {0.f, 0.f, 0.f, 0.f}; return r; }

// pack two f32 -> one u32 of 2 x bf16 (truncation), single v_perm_b32
__device__ __forceinline__ unsigned pktrunc(float lo, float hi) {
#if __has_builtin(__builtin_amdgcn_perm)
    return __builtin_amdgcn_perm(__builtin_bit_cast(unsigned, hi),
                                 __builtin_bit_cast(unsigned, lo), 0x07060302u);
#else
    return (__builtin_bit_cast(unsigned, hi) & 0xffff0000u)
         | (__builtin_bit_cast(unsigned, lo) >> 16);
#endif
}

// split 8 fp32 values into hi/lo bf16 fragments
__device__ __forceinline__ void split8(f32x4 a, f32x4 b, s16x8& hi, s16x8& lo) {
#pragma unroll
    for (int i = 0; i < 4; i++) {
        short h = f2bf(a[i]);
        hi[i] = h;
        lo[i] = f2bf(a[i] - bf2f(h));
    }
#pragma unroll
    for (int i = 0; i < 4; i++) {
        short h = f2bf(b[i]);
        hi[i + 4] = h;
        lo[i + 4] = f2bf(b[i] - bf2f(h));
    }
}

// ---------------------------------------------------------------------------
// Prep: pre-split the three 64x64 W matrices into per-lane hi/lo fragments.
// Slot layout (u32x4 units): hi at (z*8 + nt*2 + kb)*64 + ln ; lo at +1536.
// grid (3), block 256, 2 iters.
// ---------------------------------------------------------------------------
__global__ __launch_bounds__(256) void prep_w_32727650796335(
    const float* __restrict__ wq, const float* __restrict__ wk,
    const float* __restrict__ wv, u32x4* __restrict__ whl) {
    const int z = blockIdx.x;
    const float* W = (z == 0) ? wq : (z == 1) ? wk : wv;
    const f32x4* W4 = (const f32x4*)W;
#pragma unroll
    for (int it = 0; it < 2; it++) {
        int unit = threadIdx.x + 256 * it;       // 0..511
        int nt = unit >> 7, kb = (unit >> 6) & 1, ln = unit & 63;
        int g = ln >> 4, lq = ln & 15;
        f32x4 a = W4[(lq + 16 * nt) * 16 + (g + 8 * kb)];
        f32x4 b = W4[(lq + 16 * nt) * 16 + (g + 4 + 8 * kb)];
        s16x8 hi, lo;
        split8(a, b, hi, lo);
        int slot = (z * 8 + nt * 2 + kb) * 64 + ln;
        whl[slot] = __builtin_bit_cast(u32x4, hi);
        whl[slot + 1536] = __builtin_bit_cast(u32x4, lo);
    }
}

// ---------------------------------------------------------------------------
// Projection: Xp = X @ W^T + b (split-bf16 accurate). Outputs bf16:
//   z==0 (Q): single plane, fragment order (32x32x16 A-op), per 64-row chunk
//   z==1 (K): hi+lo planes, row-major [32768][64], PRE-SCALED by log2(e)
//   z==2 (V): single plane, fragment order (V^T A-op), per 64-row chunk
// W fragments pre-split by prep kernel. grid (512,3), block 256.
// ---------------------------------------------------------------------------
__global__ __launch_bounds__(256) void proj_qkv_32727650796335(
    const float* __restrict__ q_, const float* __restrict__ k_, const float* __restrict__ v_,
    const float* __restrict__ bq, const float* __restrict__ bk, const float* __restrict__ bv,
    const u32x4* __restrict__ whl,
    u16* __restrict__ qp, u16* __restrict__ kph, u16* __restrict__ kpl,
    u16* __restrict__ vp) {
    const int z = blockIdx.y;
    const float* X  = (z == 0) ? q_ : (z == 1) ? k_ : v_;
    const float* bi = (z == 0) ? bq : (z == 1) ? bk : bv;

    const int t = threadIdx.x;
    const int w = t >> 6, ln = t & 63, g = ln >> 4, lq = ln & 15;
    const int cidx = blockIdx.x;                 // 0..511 (b*64 + chunk)

    __shared__ f32x4 ldsX[1024];                 // 64 rows x 16 float4, swizzled
    __shared__ __align__(16) u16 outH[4096];     // 8KB hi-plane staging
    __shared__ __align__(16) u16 outLo[4096];    // 8KB lo-plane staging (K only)

    const f32x4* X4 = (const f32x4*)X + (size_t)cidx * 1024;
#pragma unroll
    for (int kk = 0; kk < 4; kk++) {
        int lin = t + 256 * kk;
        int r = lin >> 4, c4 = lin & 15;
        ldsX[r * 16 + (c4 ^ (r & 7))] = X4[lin];
    }
    __syncthreads();

    float bv4[4];
#pragma unroll
    for (int nt = 0; nt < 4; nt++) bv4[nt] = bi[lq + 16 * nt];

    // W fragments: pre-split hi/lo from prep kernel
    s16x8 wfh[4][2], wfl[4][2];
#pragma unroll
    for (int nt = 0; nt < 4; nt++)
#pragma unroll
        for (int kb = 0; kb < 2; kb++) {
            int slot = (z * 8 + nt * 2 + kb) * 64 + ln;
            wfh[nt][kb] = __builtin_bit_cast(s16x8, whl[slot]);
            wfl[nt][kb] = __builtin_bit_cast(s16x8, whl[slot + 1536]);
        }

    s16x8 afh[2], afl[2];
#pragma unroll
    for (int kb = 0; kb < 2; kb++) {
        f32x4 a = ldsX[(16 * w + lq) * 16 + ((g + 8 * kb) ^ (lq & 7))];
        f32x4 b = ldsX[(16 * w + lq) * 16 + ((g + 4 + 8 * kb) ^ (lq & 7))];
        split8(a, b, afh[kb], afl[kb]);
    }

    f32x4 acc[4];
#pragma unroll
    for (int nt = 0; nt < 4; nt++) acc[nt] = zero4();
#pragma unroll
    for (int kb = 0; kb < 2; kb++)
#pragma unroll
        for (int nt = 0; nt < 4; nt++) {
            acc[nt] = MFMA16(afh[kb], wfh[nt][kb], acc[nt]);
            acc[nt] = MFMA16(afh[kb], wfl[nt][kb], acc[nt]);
            acc[nt] = MFMA16(afl[kb], wfh[nt][kb], acc[nt]);
        }

    // D: row_local = 16w + 4g + r, col f = lq + 16nt  (C/D layout, m89/m91)
#pragma unroll
    for (int nt = 0; nt < 4; nt++)
#pragma unroll
        for (int r = 0; r < 4; r++) {
            float val = acc[nt][r] + bv4[nt];
            if (z == 1) val *= 1.44269504f;      // log2(e), BEFORE split
            short hi = f2bf(val);
            int row = 16 * w + 4 * g + r;
            int f = lq + 16 * nt;
            unsigned idx;
            if (z == 0) {
                idx = (unsigned)((row >> 5) * 2048 + nt * 512
                    + ((row & 31) + ((lq >> 3) & 1) * 32) * 8 + (lq & 7));
            } else if (z == 1) {
                idx = (unsigned)(row * 64 + f);
            } else {
                idx = (unsigned)((f >> 5) * 2048 + (row >> 4) * 512
                    + ((f & 31) + ((row >> 2) & 1) * 32) * 8
                    + ((row >> 3) & 1) * 4 + (row & 3));
            }
            outH[idx] = (u16)hi;
            if (z == 1) outLo[idx] = (u16)f2bf(val - bf2f(hi));
        }
    __syncthreads();

    u16* dH = (z == 0) ? qp : (z == 1) ? kph : vp;
    u32x4* d4 = (u32x4*)(dH + (size_t)cidx * 4096);
    const u32x4* sH = (const u32x4*)outH;
    d4[t] = sH[t];
    d4[t + 256] = sH[t + 256];
    if (z == 1) {
        u32x4* d4l = (u32x4*)(kpl + (size_t)cidx * 4096);
        const u32x4* sL = (const u32x4*)outLo;
        d4l[t] = sL[t];
        d4l[t + 256] = sL[t + 256];
    }
}

// ---------------------------------------------------------------------------
// Attention. Barrier-free, LDS-free: Q/V fragments streamed from L2 directly
// into MFMA operands (per-lane order matches storage exactly).
// grid: flat 8*64*nsplit blocks of 128 thr (2 independent waves of 32 i-rows).
// Flat-id mapping puts batch in bid&7 -> per-XCD working set ~2MB (L2-fit).
// ---------------------------------------------------------------------------
__global__ __launch_bounds__(128, 3) void attn_fwd_32727650796335(
    const u16* __restrict__ qp, const u16* __restrict__ kph,
    const u16* __restrict__ kpl, const u16* __restrict__ vp,
    float* __restrict__ out, float* __restrict__ pO, f32x2* __restrict__ pML,
    int nsplit) {
    const int flat = blockIdx.x;
    const int b = flat & 7;
    const int rest = flat >> 3;
    const int itile = rest & 63;                 // 64-row block tile
    const int split = rest >> 6;
    const int wv = threadIdx.x >> 6, ln = threadIdx.x & 63;
    const int i5 = ln & 31, h = ln >> 5;
    const int nc = 64 / nsplit;
    const int c0 = split * nc;

    const int irow = b * 4096 + itile * 64 + 32 * wv + i5;   // global LK row
    const u16* krh = kph + (size_t)irow * 64;
    const u16* krl = kpl + (size_t)irow * 64;
    s16x8 kfh[4], kfl[4];
#pragma unroll
    for (int ks = 0; ks < 4; ks++) {
        kfh[ks] = *(const s16x8*)(krh + 16 * ks + 8 * h);
        kfl[ks] = *(const s16x8*)(krl + 16 * ks + 8 * h);
    }

    f32x16 oacc0 = {}, oacc1 = {};
    float m = -__builtin_inff();
    float lsum = 0.f;

    const u32x4* qsrc = (const u32x4*)(qp + (size_t)(b * 64) * 4096);
    const u32x4* vsrc = (const u32x4*)(vp + (size_t)(b * 64) * 4096);

    for (int cc = 0; cc < nc; cc++) {
        const u32x4* qc = qsrc + (size_t)(c0 + cc) * 512 + ln;
        const u32x4* vc = vsrc + (size_t)(c0 + cc) * 512 + ln;

        // ---- Q fragments straight from L2 (coalesced 1KB per load) ----
        u32x4 q00 = qc[0],   q01 = qc[64],  q02 = qc[128], q03 = qc[192];
        u32x4 q10 = qc[256], q11 = qc[320], q12 = qc[384], q13 = qc[448];

        // ---- QK^T : S^T 32x32 tiles t2=0,1 ; S = Q*(Kh+Kl); 16 MFMA ----
        f32x16 s0 = {}, s1 = {};
        __builtin_amdgcn_s_setprio(1);
#define QKS(qa_, qb_, ks_) do {                                         \
        s16x8 q0_ = __builtin_bit_cast(s16x8, qa_);                     \
        s16x8 q1_ = __builtin_bit_cast(s16x8, qb_);                     \
        s0 = MFMA32(q0_, kfh[ks_], s0);                                 \
        s1 = MFMA32(q1_, kfh[ks_], s1);                                 \
        s0 = MFMA32(q0_, kfl[ks_], s0);                                 \
        s1 = MFMA32(q1_, kfl[ks_], s1); } while (0)
        QKS(q00, q10, 0);
        QKS(q01, q11, 1);
        QKS(q02, q12, 2);
        QKS(q03, q13, 3);
#undef QKS
        __builtin_amdgcn_s_setprio(0);

        // ---- V fragments (issue early, consumed after softmax) ----
        u32x4 v00 = vc[0],   v01 = vc[64],  v02 = vc[128], v03 = vc[192];
        u32x4 v10 = vc[256], v11 = vc[320], v12 = vc[384], v13 = vc[448];

        // ---- online softmax over j (exp2 domain): max3 tree ----
        float mx[11];
#pragma unroll
        for (int r = 0; r < 10; r++)              // 32 values -> 10 triples + pair
            mx[r] = fmaxf(fmaxf((r < 8 ? s0[2 * r] : s1[2 * (r - 8)]),
                                (r < 8 ? s0[2 * r + 1] : s1[2 * (r - 8) + 1])),
                          (r < 8 ? (r < 5 ? s1[r + 6] : s0[r + 11])
                                 : s1[2 * (r - 8) + 4]));
        mx[10] = fmaxf(s1[2], s1[3]);             // leftovers: s1[2],s1[3]
        float a0 = fmaxf(fmaxf(mx[0], mx[1]), mx[2]);
        float a1 = fmaxf(fmaxf(mx[3], mx[4]), mx[5]);
        float a2 = fmaxf(fmaxf(mx[6], mx[7]), mx[8]);
        float a3 = fmaxf(mx[9], mx[10]);
        float pmax = fmaxf(fmaxf(a0, a1), fmaxf(a2, a3));
        pmax = fmaxf(pmax, __shfl_xor(pmax, 32));

        if (!__all(pmax <= m + 8.f)) {            // T13: defer-max, THR=8 (P<=256)
            float mnew = fmaxf(m, pmax);
            float corr = FEXP2(m - mnew);         // first chunk: 2^-inf = 0
            lsum *= corr;
#pragma unroll
            for (int r = 0; r < 16; r++) { oacc0[r] *= corr; oacc1[r] *= corr; }
            m = mnew;
        }

        float psum = 0.f;
#pragma unroll
        for (int r = 0; r < 16; r++) {
            s0[r] = FEXP2(s0[r] - m);
            s1[r] = FEXP2(s1[r] - m);
            psum += s0[r] + s1[r];
        }
        psum += __shfl_xor(psum, 32);
        lsum += psum;

        // pack P to bf16 (truncation via v_perm): pf[qh] <- s0, pf[2+qh] <- s1
        s16x8 pf[4];
#pragma unroll
        for (int qh = 0; qh < 2; qh++) {
            u32x4 pa, pb;
#pragma unroll
            for (int r = 0; r < 4; r++) {
                pa[r] = pktrunc(s0[8 * qh + 2 * r], s0[8 * qh + 2 * r + 1]);
                pb[r] = pktrunc(s1[8 * qh + 2 * r], s1[8 * qh + 2 * r + 1]);
            }
            pf[qh]     = __builtin_bit_cast(s16x8, pa);
            pf[2 + qh] = __builtin_bit_cast(s16x8, pb);
        }

        // ---- PV : O^T[f,i] += V^T @ P^T (fragment-ordered V from L2) ----
        __builtin_amdgcn_s_setprio(1);
#define PVS(va_, vb_, s4_) do {                                         \
        oacc0 = MFMA32(__builtin_bit_cast(s16x8, va_), pf[s4_], oacc0); \
        oacc1 = MFMA32(__builtin_bit_cast(s16x8, vb_), pf[s4_], oacc1); } while (0)
        PVS(v00, v10, 0);
        PVS(v01, v11, 1);
        PVS(v02, v12, 2);
        PVS(v03, v13, 3);
#undef PVS
        __builtin_amdgcn_s_setprio(0);
    }

    // ---- epilogue: f = 32*ft2 + 8*q + 4*h + r ; i = i5 ----
    if (nsplit == 1) {
        float inv = 1.f / lsum;
#pragma unroll
        for (int q = 0; q < 4; q++) {
            f32x4 o0, o1;
#pragma unroll
            for (int r = 0; r < 4; r++) {
                o0[r] = oacc0[4 * q + r] * inv;
                o1[r] = oacc1[4 * q + r] * inv;
            }
            *(f32x4*)(out + (size_t)irow * 64 + 8 * q + 4 * h) = o0;
            *(f32x4*)(out + (size_t)irow * 64 + 32 + 8 * q + 4 * h) = o1;
        }
    } else {
        size_t base = ((size_t)split * 32768 + (size_t)irow) * 64;
#pragma unroll
        for (int q = 0; q < 4; q++) {
            f32x4 o0, o1;
#pragma unroll
            for (int r = 0; r < 4; r++) {
                o0[r] = oacc0[4 * q + r];
                o1[r] = oacc1[4 * q + r];
            }
            *(f32x4*)(pO + base + 8 * q + 4 * h) = o0;
            *(f32x4*)(pO + base + 32 + 8 * q + 4 * h) = o1;
        }
        if (ln < 32) {
            f32x2 ml; ml[0] = m; ml[1] = lsum;
            pML[(size_t)split * 32768 + irow] = ml;
        }
    }
}

// ---------------------------------------------------------------------------
// Combine: merge nsplit partials (fp32 pO, log2-domain m). grid 512, block 256.
// ---------------------------------------------------------------------------
__global__ __launch_bounds__(256) void combine_32727650796335(
    const float* __restrict__ pO, const f32x2* __restrict__ pML,
    float* __restrict__ out, int nsplit) {
    const int bt = blockIdx.x;
    const int t = threadIdx.x;
    const int row = t >> 2, fb = (t & 3) << 4;
    const size_t grow = (size_t)bt * 64 + row;

    float M = -__builtin_inff();
#pragma unroll
    for (int s = 0; s < 4; s++)
        if (s < nsplit) M = fmaxf(M, pML[(size_t)s * 32768 + grow][0]);

    float wgt[4];
    float W = 0.f;
#pragma unroll
    for (int s = 0; s < 4; s++) {
        if (s < nsplit) {
            f32x2 ml = pML[(size_t)s * 32768 + grow];
            wgt[s] = exp2f(ml[0] - M);
            W += wgt[s] * ml[1];
        } else wgt[s] = 0.f;
    }
    float inv = 1.f / W;

#pragma unroll
    for (int ff = 0; ff < 16; ff += 4) {
        f32x4 acc = zero4();
#pragma unroll
        for (int s = 0; s < 4; s++)
            if (s < nsplit)
                acc += wgt[s] * *(const f32x4*)(pO + ((size_t)s * 32768 + grow) * 64 + fb + ff);
        *(f32x4*)(out + grow * 64 + fb + ff) = acc * inv;
    }
}

// ---------------------------------------------------------------------------
extern "C" void kernel_launch(void* const* d_in, const int* in_sizes, int n_in,
                              void* d_out, int out_size, void* d_ws, size_t ws_size,
                              hipStream_t stream) {
    (void)in_sizes; (void)n_in; (void)out_size;
    const float* q_ = (const float*)d_in[0];
    const float* k_ = (const float*)d_in[1];
    const float* v_ = (const float*)d_in[2];
    const float* wq = (const float*)d_in[3];
    const float* bq = (const float*)d_in[4];
    const float* wk = (const float*)d_in[5];
    const float* bk = (const float*)d_in[6];
    const float* wv = (const float*)d_in[7];
    const float* bv = (const float*)d_in[8];

    const size_t PLANE = (size_t)8 * 4096 * 64;   // 2M bf16 elements (4 MB)
    u16* qp  = (u16*)d_ws;
    u16* kph = qp + PLANE;
    u16* kpl = kph + PLANE;
    u16* vp  = kpl + PLANE;
    const size_t planes_bytes = 4 * PLANE * sizeof(u16);          // 16 MB
    u32x4* whl = (u32x4*)((char*)d_ws + planes_bytes);            // 48 KB
    const size_t whl_bytes = 3072 * sizeof(u32x4);

    auto fits = [&](int js) {
        size_t need = planes_bytes + whl_bytes
                    + (size_t)js * 32768 * 64 * sizeof(float)     // partial O fp32
                    + (size_t)js * 32768 * sizeof(f32x2);         // partial (m,l)
        return need <= ws_size;
    };
    int nsplit = fits(4) ? 4 : (fits(2) ? 2 : 1);

    float* pO  = (float*)((char*)d_ws + planes_bytes + whl_bytes);
    f32x2* pML = (f32x2*)((char*)d_ws + planes_bytes + whl_bytes
                          + (size_t)nsplit * 32768 * 64 * sizeof(float));

    prep_w_32727650796335<<<dim3(3, 1, 1), 256, 0, stream>>>(wq, wk, wv, whl);
    proj_qkv_32727650796335<<<dim3(512, 3, 1), 256, 0, stream>>>(
        q_, k_, v_, bq, bk, bv, whl, qp, kph, kpl, vp);
    attn_fwd_32727650796335<<<dim3(8 * 64 * nsplit, 1, 1), 128, 0, stream>>>(
        qp, kph, kpl, vp, (float*)d_out, pO, pML, nsplit);
    if (nsplit > 1)
        combine_32727650796335<<<dim3(512, 1, 1), 256, 0, stream>>>(
            pO, pML, (float*)d_out, nsplit);
}

// Round 11
// 108.632 us; speedup vs baseline: 1.0360x; 1.0360x over previous
//
#include <hip/hip_runtime.h>

// ---------------------------------------------------------------------------
// DotProductAttention: out[b,i,f] = softmax_j(<K_i, Q_j>) @ V[j,f]
// Q single bf16 plane; K hi+lo (registers); 32x32x16 bf16 MFMA.
// K pre-scaled by log2(e) -> exp2-domain softmax. B=8, L=4096, F=64.
// R11: R9 attn (LDS dbuf, 1 barrier/chunk, setprio, max3, defer-max)
//      + R10 prep_w/proj (W hi/lo pre-split). Bit-identical numerics.
// ---------------------------------------------------------------------------

typedef unsigned short u16;
typedef __attribute__((ext_vector_type(4))) unsigned int u32x4;
typedef __attribute__((ext_vector_type(4))) float f32x4;
typedef __attribute__((ext_vector_type(16))) float f32x16;
typedef __attribute__((ext_vector_type(2))) float f32x2;
typedef __attribute__((ext_vector_type(8))) short s16x8;

#define MFMA32(a, bb, c) __builtin_amdgcn_mfma_f32_32x32x16_bf16((a), (bb), (c), 0, 0, 0)
#define MFMA16(a, bb, c) __builtin_amdgcn_mfma_f32_16x16x32_bf16((a), (bb), (c), 0, 0, 0)

#if __has_builtin(__builtin_amdgcn_exp2f)
#define FEXP2(x) __builtin_amdgcn_exp2f(x)
#else
#define FEXP2(x) exp2f(x)
#endif

__device__ __forceinline__ short f2bf(float x) {
    unsigned u = __builtin_bit_cast(unsigned, x);
    u += 0x7fffu + ((u >> 16) & 1u);   // round-to-nearest-even
    return (short)(u >> 16);
}
__device__ __forceinline__ float bf2f(short h) {
    unsigned u = ((unsigned)(u16)h) << 16;
    return __builtin_bit_cast(float, u);
}
__device__ __forceinline__ f32x4 zero4() { f32x4 r = {0.f, 0.f, 0.f, 0.f}; return r; }

// pack two f32 -> one u32 of 2 x bf16 (truncation), single v_perm_b32
__device__ __forceinline__ unsigned pktrunc(float lo, float hi) {
#if __has_builtin(__builtin_amdgcn_perm)
    return __builtin_amdgcn_perm(__builtin_bit_cast(unsigned, hi),
                                 __builtin_bit_cast(unsigned, lo), 0x07060302u);
#else
    return (__builtin_bit_cast(unsigned, hi) & 0xffff0000u)
         | (__builtin_bit_cast(unsigned, lo) >> 16);
#endif
}

// split 8 fp32 values into hi/lo bf16 fragments
__device__ __forceinline__ void split8(f32x4 a, f32x4 b, s16x8& hi, s16x8& lo) {
#pragma unroll
    for (int i = 0; i < 4; i++) {
        short h = f2bf(a[i]);
        hi[i] = h;
        lo[i] = f2bf(a[i] - bf2f(h));
    }
#pragma unroll
    for (int i = 0; i < 4; i++) {
        short h = f2bf(b[i]);
        hi[i + 4] = h;
        lo[i + 4] = f2bf(b[i] - bf2f(h));
    }
}

// ---------------------------------------------------------------------------
// Prep: pre-split the three 64x64 W matrices into per-lane hi/lo fragments.
// Slot layout (u32x4 units): hi at (z*8 + nt*2 + kb)*64 + ln ; lo at +1536.
// grid (3), block 256, 2 iters.
// ---------------------------------------------------------------------------
__global__ __launch_bounds__(256) void prep_w_32727650796335(
    const float* __restrict__ wq, const float* __restrict__ wk,
    const float* __restrict__ wv, u32x4* __restrict__ whl) {
    const int z = blockIdx.x;
    const float* W = (z == 0) ? wq : (z == 1) ? wk : wv;
    const f32x4* W4 = (const f32x4*)W;
#pragma unroll
    for (int it = 0; it < 2; it++) {
        int unit = threadIdx.x + 256 * it;       // 0..511
        int nt = unit >> 7, kb = (unit >> 6) & 1, ln = unit & 63;
        int g = ln >> 4, lq = ln & 15;
        f32x4 a = W4[(lq + 16 * nt) * 16 + (g + 8 * kb)];
        f32x4 b = W4[(lq + 16 * nt) * 16 + (g + 4 + 8 * kb)];
        s16x8 hi, lo;
        split8(a, b, hi, lo);
        int slot = (z * 8 + nt * 2 + kb) * 64 + ln;
        whl[slot] = __builtin_bit_cast(u32x4, hi);
        whl[slot + 1536] = __builtin_bit_cast(u32x4, lo);
    }
}

// ---------------------------------------------------------------------------
// Projection: Xp = X @ W^T + b (split-bf16 accurate). Outputs bf16:
//   z==0 (Q): single plane, fragment order (32x32x16 A-op), per 64-row chunk
//   z==1 (K): hi+lo planes, row-major [32768][64], PRE-SCALED by log2(e)
//   z==2 (V): single plane, fragment order (V^T A-op), per 64-row chunk
// W fragments pre-split by prep kernel. grid (512,3), block 256.
// ---------------------------------------------------------------------------
__global__ __launch_bounds__(256) void proj_qkv_32727650796335(
    const float* __restrict__ q_, const float* __restrict__ k_, const float* __restrict__ v_,
    const float* __restrict__ bq, const float* __restrict__ bk, const float* __restrict__ bv,
    const u32x4* __restrict__ whl,
    u16* __restrict__ qp, u16* __restrict__ kph, u16* __restrict__ kpl,
    u16* __restrict__ vp) {
    const int z = blockIdx.y;
    const float* X  = (z == 0) ? q_ : (z == 1) ? k_ : v_;
    const float* bi = (z == 0) ? bq : (z == 1) ? bk : bv;

    const int t = threadIdx.x;
    const int w = t >> 6, ln = t & 63, g = ln >> 4, lq = ln & 15;
    const int cidx = blockIdx.x;                 // 0..511 (b*64 + chunk)

    __shared__ f32x4 ldsX[1024];                 // 64 rows x 16 float4, swizzled
    __shared__ __align__(16) u16 outH[4096];     // 8KB hi-plane staging
    __shared__ __align__(16) u16 outLo[4096];    // 8KB lo-plane staging (K only)

    const f32x4* X4 = (const f32x4*)X + (size_t)cidx * 1024;
#pragma unroll
    for (int kk = 0; kk < 4; kk++) {
        int lin = t + 256 * kk;
        int r = lin >> 4, c4 = lin & 15;
        ldsX[r * 16 + (c4 ^ (r & 7))] = X4[lin];
    }
    __syncthreads();

    float bv4[4];
#pragma unroll
    for (int nt = 0; nt < 4; nt++) bv4[nt] = bi[lq + 16 * nt];

    // W fragments: pre-split hi/lo from prep kernel
    s16x8 wfh[4][2], wfl[4][2];
#pragma unroll
    for (int nt = 0; nt < 4; nt++)
#pragma unroll
        for (int kb = 0; kb < 2; kb++) {
            int slot = (z * 8 + nt * 2 + kb) * 64 + ln;
            wfh[nt][kb] = __builtin_bit_cast(s16x8, whl[slot]);
            wfl[nt][kb] = __builtin_bit_cast(s16x8, whl[slot + 1536]);
        }

    s16x8 afh[2], afl[2];
#pragma unroll
    for (int kb = 0; kb < 2; kb++) {
        f32x4 a = ldsX[(16 * w + lq) * 16 + ((g + 8 * kb) ^ (lq & 7))];
        f32x4 b = ldsX[(16 * w + lq) * 16 + ((g + 4 + 8 * kb) ^ (lq & 7))];
        split8(a, b, afh[kb], afl[kb]);
    }

    f32x4 acc[4];
#pragma unroll
    for (int nt = 0; nt < 4; nt++) acc[nt] = zero4();
#pragma unroll
    for (int kb = 0; kb < 2; kb++)
#pragma unroll
        for (int nt = 0; nt < 4; nt++) {
            acc[nt] = MFMA16(afh[kb], wfh[nt][kb], acc[nt]);
            acc[nt] = MFMA16(afh[kb], wfl[nt][kb], acc[nt]);
            acc[nt] = MFMA16(afl[kb], wfh[nt][kb], acc[nt]);
        }

    // D: row_local = 16w + 4g + r, col f = lq + 16nt  (C/D layout, m89/m91)
#pragma unroll
    for (int nt = 0; nt < 4; nt++)
#pragma unroll
        for (int r = 0; r < 4; r++) {
            float val = acc[nt][r] + bv4[nt];
            if (z == 1) val *= 1.44269504f;      // log2(e), BEFORE split
            short hi = f2bf(val);
            int row = 16 * w + 4 * g + r;
            int f = lq + 16 * nt;
            unsigned idx;
            if (z == 0) {
                idx = (unsigned)((row >> 5) * 2048 + nt * 512
                    + ((row & 31) + ((lq >> 3) & 1) * 32) * 8 + (lq & 7));
            } else if (z == 1) {
                idx = (unsigned)(row * 64 + f);
            } else {
                idx = (unsigned)((f >> 5) * 2048 + (row >> 4) * 512
                    + ((f & 31) + ((row >> 2) & 1) * 32) * 8
                    + ((row >> 3) & 1) * 4 + (row & 3));
            }
            outH[idx] = (u16)hi;
            if (z == 1) outLo[idx] = (u16)f2bf(val - bf2f(hi));
        }
    __syncthreads();

    u16* dH = (z == 0) ? qp : (z == 1) ? kph : vp;
    u32x4* d4 = (u32x4*)(dH + (size_t)cidx * 4096);
    const u32x4* sH = (const u32x4*)outH;
    d4[t] = sH[t];
    d4[t + 256] = sH[t + 256];
    if (z == 1) {
        u32x4* d4l = (u32x4*)(kpl + (size_t)cidx * 4096);
        const u32x4* sL = (const u32x4*)outLo;
        d4l[t] = sL[t];
        d4l[t + 256] = sL[t + 256];
    }
}

// ---------------------------------------------------------------------------
// Attention (R9 structure). grid (32 itiles, 8 batches, nsplit), block 256.
// Wave w: i-strip [itile*128+32w, +32); lane i = ln&31, h = ln>>5.
// S^T 32x32 tiles: S = Q*(Kh+Kl), 16 MFMA; exp2-domain online softmax,
// defer-max THR=8; P packed by v_perm truncation, zero-shuffle into PV.
// Double-buffered LDS: ONE barrier per chunk.
// ---------------------------------------------------------------------------
__global__ __launch_bounds__(256, 4) void attn_fwd_32727650796335(
    const u16* __restrict__ qp, const u16* __restrict__ kph,
    const u16* __restrict__ kpl, const u16* __restrict__ vp,
    float* __restrict__ out, float* __restrict__ pO, f32x2* __restrict__ pML,
    int nsplit) {
    const int t = threadIdx.x;
    const int w = t >> 6, ln = t & 63, i5 = ln & 31, h = ln >> 5;
    const int itile = blockIdx.x, b = blockIdx.y, split = blockIdx.z;
    const int nc = 64 / nsplit;
    const int c0 = split * nc;

    __shared__ u32x4 ldsbuf[2][1024];            // per buf: Q [0,8K), V [8K,16K)

    const int irow = b * 4096 + itile * 128 + 32 * w + i5;   // global LK row
    const u16* krh = kph + (size_t)irow * 64;
    const u16* krl = kpl + (size_t)irow * 64;
    s16x8 kfh[4], kfl[4];
#pragma unroll
    for (int ks = 0; ks < 4; ks++) {
        kfh[ks] = *(const s16x8*)(krh + 16 * ks + 8 * h);
        kfl[ks] = *(const s16x8*)(krl + 16 * ks + 8 * h);
    }

    f32x16 oacc0 = {}, oacc1 = {};
    float m = -__builtin_inff();
    float lsum = 0.f;

    const u32x4* qsrc = (const u32x4*)(qp + (size_t)(b * 64) * 4096);
    const u32x4* vsrc = (const u32x4*)(vp + (size_t)(b * 64) * 4096);

    u32x4 qa, qb, va, vb;
#define LOADC(c) do { size_t o_ = (size_t)(c) * 512 + t;      \
        qa = qsrc[o_]; qb = qsrc[o_ + 256];                   \
        va = vsrc[o_]; vb = vsrc[o_ + 256]; } while (0)

    // prologue: fill buffer 0
    LOADC(c0);
    ldsbuf[0][t] = qa;
    ldsbuf[0][t + 256] = qb;
    ldsbuf[0][t + 512] = va;
    ldsbuf[0][t + 768] = vb;

    int cur = 0;
    for (int cc = 0; cc < nc; cc++) {
        __syncthreads();                          // buf[cur] fully written
        if (cc + 1 < nc) LOADC(c0 + cc + 1);      // T14: issue next loads early
        const char* ldsc = (const char*)ldsbuf[cur];

        // ---- QK^T : S^T 32x32 tiles t2=0,1 ; S = Q*(Kh+Kl); 16 MFMA ----
        f32x16 s0 = {}, s1 = {};
        __builtin_amdgcn_s_setprio(1);
#pragma unroll
        for (int ks = 0; ks < 4; ks++) {
            const int fo = ks * 1024 + ln * 16;
            s16x8 q0 = *(const s16x8*)(ldsc + fo);
            s16x8 q1 = *(const s16x8*)(ldsc + 4096 + fo);
            s0 = MFMA32(q0, kfh[ks], s0);
            s1 = MFMA32(q1, kfh[ks], s1);
            s0 = MFMA32(q0, kfl[ks], s0);
            s1 = MFMA32(q1, kfl[ks], s1);
        }
        __builtin_amdgcn_s_setprio(0);

        // ---- online softmax over j (exp2 domain): max3 tree ----
        float mx[11];
#pragma unroll
        for (int r = 0; r < 10; r++)              // 32 values -> 10 triples + pair
            mx[r] = fmaxf(fmaxf((r < 8 ? s0[2 * r] : s1[2 * (r - 8)]),
                                (r < 8 ? s0[2 * r + 1] : s1[2 * (r - 8) + 1])),
                          (r < 8 ? (r < 5 ? s1[r + 6] : s0[r + 11])
                                 : s1[2 * (r - 8) + 4]));
        mx[10] = fmaxf(s1[2], s1[3]);             // leftovers: s1[2],s1[3]
        float a0 = fmaxf(fmaxf(mx[0], mx[1]), mx[2]);
        float a1 = fmaxf(fmaxf(mx[3], mx[4]), mx[5]);
        float a2 = fmaxf(fmaxf(mx[6], mx[7]), mx[8]);
        float a3 = fmaxf(mx[9], mx[10]);
        float pmax = fmaxf(fmaxf(a0, a1), fmaxf(a2, a3));
        pmax = fmaxf(pmax, __shfl_xor(pmax, 32));

        if (!__all(pmax <= m + 8.f)) {            // T13: defer-max, THR=8 (P<=256)
            float mnew = fmaxf(m, pmax);
            float corr = FEXP2(m - mnew);         // first chunk: 2^-inf = 0
            lsum *= corr;
#pragma unroll
            for (int r = 0; r < 16; r++) { oacc0[r] *= corr; oacc1[r] *= corr; }
            m = mnew;
        }

        float psum = 0.f;
#pragma unroll
        for (int r = 0; r < 16; r++) {
            s0[r] = FEXP2(s0[r] - m);
            s1[r] = FEXP2(s1[r] - m);
            psum += s0[r] + s1[r];
        }
        psum += __shfl_xor(psum, 32);
        lsum += psum;

        // pack P to bf16 (truncation via v_perm): pf[qh] <- s0, pf[2+qh] <- s1
        s16x8 pf[4];
#pragma unroll
        for (int qh = 0; qh < 2; qh++) {
            u32x4 pa, pb;
#pragma unroll
            for (int r = 0; r < 4; r++) {
                pa[r] = pktrunc(s0[8 * qh + 2 * r], s0[8 * qh + 2 * r + 1]);
                pb[r] = pktrunc(s1[8 * qh + 2 * r], s1[8 * qh + 2 * r + 1]);
            }
            pf[qh]     = __builtin_bit_cast(s16x8, pa);
            pf[2 + qh] = __builtin_bit_cast(s16x8, pb);
        }

        // ---- PV : O^T[f,i] += V^T @ P^T (fragment-ordered V, linear reads) ----
        __builtin_amdgcn_s_setprio(1);
#pragma unroll
        for (int s4 = 0; s4 < 4; s4++) {
            s16x8 vf0 = *(const s16x8*)(ldsc + 8192 + s4 * 1024 + ln * 16);
            s16x8 vf1 = *(const s16x8*)(ldsc + 12288 + s4 * 1024 + ln * 16);
            oacc0 = MFMA32(vf0, pf[s4], oacc0);
            oacc1 = MFMA32(vf1, pf[s4], oacc1);
        }
        __builtin_amdgcn_s_setprio(0);

        // write NEXT chunk into the other buffer (no barrier needed: disjoint)
        if (cc + 1 < nc) {
            ldsbuf[cur ^ 1][t] = qa;
            ldsbuf[cur ^ 1][t + 256] = qb;
            ldsbuf[cur ^ 1][t + 512] = va;
            ldsbuf[cur ^ 1][t + 768] = vb;
        }
        cur ^= 1;
    }
#undef LOADC

    // ---- epilogue: f = 32*ft2 + 8*q + 4*h + r ; i = i5 ----
    if (nsplit == 1) {
        float inv = 1.f / lsum;
#pragma unroll
        for (int q = 0; q < 4; q++) {
            f32x4 o0, o1;
#pragma unroll
            for (int r = 0; r < 4; r++) {
                o0[r] = oacc0[4 * q + r] * inv;
                o1[r] = oacc1[4 * q + r] * inv;
            }
            *(f32x4*)(out + (size_t)irow * 64 + 8 * q + 4 * h) = o0;
            *(f32x4*)(out + (size_t)irow * 64 + 32 + 8 * q + 4 * h) = o1;
        }
    } else {
        size_t base = ((size_t)split * 32768 + (size_t)irow) * 64;
#pragma unroll
        for (int q = 0; q < 4; q++) {
            f32x4 o0, o1;
#pragma unroll
            for (int r = 0; r < 4; r++) {
                o0[r] = oacc0[4 * q + r];
                o1[r] = oacc1[4 * q + r];
            }
            *(f32x4*)(pO + base + 8 * q + 4 * h) = o0;
            *(f32x4*)(pO + base + 32 + 8 * q + 4 * h) = o1;
        }
        if (ln < 32) {
            f32x2 ml; ml[0] = m; ml[1] = lsum;
            pML[(size_t)split * 32768 + irow] = ml;
        }
    }
}

// ---------------------------------------------------------------------------
// Combine: merge nsplit partials (fp32 pO, log2-domain m). grid 512, block 256.
// ---------------------------------------------------------------------------
__global__ __launch_bounds__(256) void combine_32727650796335(
    const float* __restrict__ pO, const f32x2* __restrict__ pML,
    float* __restrict__ out, int nsplit) {
    const int bt = blockIdx.x;
    const int t = threadIdx.x;
    const int row = t >> 2, fb = (t & 3) << 4;
    const size_t grow = (size_t)bt * 64 + row;

    float M = -__builtin_inff();
#pragma unroll
    for (int s = 0; s < 4; s++)
        if (s < nsplit) M = fmaxf(M, pML[(size_t)s * 32768 + grow][0]);

    float wgt[4];
    float W = 0.f;
#pragma unroll
    for (int s = 0; s < 4; s++) {
        if (s < nsplit) {
            f32x2 ml = pML[(size_t)s * 32768 + grow];
            wgt[s] = exp2f(ml[0] - M);
            W += wgt[s] * ml[1];
        } else wgt[s] = 0.f;
    }
    float inv = 1.f / W;

#pragma unroll
    for (int ff = 0; ff < 16; ff += 4) {
        f32x4 acc = zero4();
#pragma unroll
        for (int s = 0; s < 4; s++)
            if (s < nsplit)
                acc += wgt[s] * *(const f32x4*)(pO + ((size_t)s * 32768 + grow) * 64 + fb + ff);
        *(f32x4*)(out + grow * 64 + fb + ff) = acc * inv;
    }
}

// ---------------------------------------------------------------------------
extern "C" void kernel_launch(void* const* d_in, const int* in_sizes, int n_in,
                              void* d_out, int out_size, void* d_ws, size_t ws_size,
                              hipStream_t stream) {
    (void)in_sizes; (void)n_in; (void)out_size;
    const float* q_ = (const float*)d_in[0];
    const float* k_ = (const float*)d_in[1];
    const float* v_ = (const float*)d_in[2];
    const float* wq = (const float*)d_in[3];
    const float* bq = (const float*)d_in[4];
    const float* wk = (const float*)d_in[5];
    const float* bk = (const float*)d_in[6];
    const float* wv = (const float*)d_in[7];
    const float* bv = (const float*)d_in[8];

    const size_t PLANE = (size_t)8 * 4096 * 64;   // 2M bf16 elements (4 MB)
    u16* qp  = (u16*)d_ws;
    u16* kph = qp + PLANE;
    u16* kpl = kph + PLANE;
    u16* vp  = kpl + PLANE;
    const size_t planes_bytes = 4 * PLANE * sizeof(u16);          // 16 MB
    u32x4* whl = (u32x4*)((char*)d_ws + planes_bytes);            // 48 KB
    const size_t whl_bytes = 3072 * sizeof(u32x4);

    auto fits = [&](int js) {
        size_t need = planes_bytes + whl_bytes
                    + (size_t)js * 32768 * 64 * sizeof(float)     // partial O fp32
                    + (size_t)js * 32768 * sizeof(f32x2);         // partial (m,l)
        return need <= ws_size;
    };
    int nsplit = fits(4) ? 4 : (fits(2) ? 2 : 1);

    float* pO  = (float*)((char*)d_ws + planes_bytes + whl_bytes);
    f32x2* pML = (f32x2*)((char*)d_ws + planes_bytes + whl_bytes
                          + (size_t)nsplit * 32768 * 64 * sizeof(float));

    prep_w_32727650796335<<<dim3(3, 1, 1), 256, 0, stream>>>(wq, wk, wv, whl);
    proj_qkv_32727650796335<<<dim3(512, 3, 1), 256, 0, stream>>>(
        q_, k_, v_, bq, bk, bv, whl, qp, kph, kpl, vp);
    attn_fwd_32727650796335<<<dim3(32, 8, nsplit), 256, 0, stream>>>(
        qp, kph, kpl, vp, (float*)d_out, pO, pML, nsplit);
    if (nsplit > 1)
        combine_32727650796335<<<dim3(512, 1, 1), 256, 0, stream>>>(
            pO, pML, (float*)d_out, nsplit);
}